// Round 3
// baseline (480.371 us; speedup 1.0000x reference)
//
#include <hip/hip_runtime.h>
#include <hip/hip_bf16.h>
#include <math.h>

#define EDIM 256
#define HDIM 256
#define BDIM 64
#define TDIM 2048
#define NC   64
#define TC   32
#define CPB  2      // chunks per persistent block (512-thread blocks)

typedef __attribute__((ext_vector_type(8)))  short  short8;
typedef __attribute__((ext_vector_type(4)))  float  floatx4;
typedef __attribute__((ext_vector_type(4)))  unsigned int uintx4;

__device__ __forceinline__ unsigned short f2bf(float f) {
    unsigned int u = __float_as_uint(f);
    u += 0x7FFFu + ((u >> 16) & 1u);      // RNE
    return (unsigned short)(u >> 16);
}
__device__ __forceinline__ unsigned int pk2(float a, float b) {
    return (unsigned int)f2bf(a) | ((unsigned int)f2bf(b) << 16);
}
__device__ __forceinline__ float sigm(float x) {
    return __builtin_amdgcn_rcpf(1.f + __expf(-x));
}
__device__ __forceinline__ float tanh_fast(float x) {
    return fmaf(-2.f, __builtin_amdgcn_rcpf(1.f + __expf(2.f * x)), 1.f);
}

// Pack kernel:
//  bx < 256 : Wp fragment-pack.
//  bx >= 256 (mode==1): emb -> bf16 table (halves the scattered bytes the
//                       mfma kernel gathers; table is L2/L3-resident).
__global__ __launch_bounds__(256) void qrnn_pack(
    const float* __restrict__ Wq, const float* __restrict__ emb,
    unsigned short* __restrict__ Wp, unsigned short* __restrict__ ebf,
    int mode)
{
    const int bx = blockIdx.x;
    if (bx < 256) {
        const int nt = (bx >> 3) & 7;
        const int hg = bx >> 6;
        const int ks = bx & 7;
        const int t = threadIdx.x;
        const int lane = t >> 2, pj = t & 3;
        const int col = lane & 15, q = lane >> 4;
        const int h = hg * 64 + (nt & 3) * 16 + col;
        const int c = (nt < 4) ? h : (HDIM + h);
        const int k = ks * 32 + q * 8 + pj * 2;
        unsigned int v = pk2(Wq[k * (3 * HDIM) + c], Wq[(k + 1) * (3 * HDIM) + c]);
        *(unsigned int*)(Wp + (size_t)bx * 512 + lane * 8 + pj * 2) = v;
    } else if (mode == 1) {
        size_t i = ((size_t)(bx - 256) * 256 + threadIdx.x) * 8;
        floatx4 a = *(const floatx4*)(emb + i);
        floatx4 b = *(const floatx4*)(emb + i + 4);
        uintx4 o = {pk2(a.x, a.y), pk2(a.z, a.w), pk2(b.x, b.y), pk2(b.z, b.w)};
        *(uintx4*)(ebf + i) = o;
    }
}

// Main: 512-thread persistent block = 2 chunks x 16 batches x 64 h.
// 8 waves/block, 64 KB LDS -> 2 blocks/CU co-resident = 16 waves/CU
// (4 waves/SIMD), double round-2's latency hiding.  B (weights) staged to
// LDS once; chunk loop is barrier-free.  A gathered per-lane from the bf16
// emb table (MODE 1) or f32 emb (MODE 0) with a 3-slot (2-ahead) pipeline.
// Grid 32x4x4: linear id = cg + 32*bg + 128*hg -> XCD = cg%8, so the 4 hg
// siblings of each (cg,bg) share an XCD and their redundant A reads L2-hit.
template<int MODE>
__global__ __launch_bounds__(512, 4) void qrnn_mfma(
    const int* __restrict__ X, const float* __restrict__ emb,
    const unsigned short* __restrict__ ebf, const unsigned short* __restrict__ Wp,
    const float* __restrict__ bq, float* __restrict__ wsA, float* __restrict__ wsB)
{
    __shared__ __align__(16) short Bsh[32768];   // 64 KB: [nt][ks][64 lanes][8]

    const int tid = threadIdx.x;
    const int cg = blockIdx.x, bg = blockIdx.y, hg = blockIdx.z;
    const int lane = tid & 63, w = tid >> 6;     // w in [0,8)
    const int col = lane & 15, q = lane >> 4;

    // Stage B slice (64 KB, all ks) once: 64 rows / 8 waves = 8 each.
    const unsigned short* wpb = Wp + (size_t)hg * 32768;
#pragma unroll
    for (int i = 0; i < 8; ++i) {
        const int ch = w * 8 + i;           // wave-uniform
        __builtin_amdgcn_global_load_lds(
            (const __attribute__((address_space(1))) unsigned int*)(wpb + ch * 512 + lane * 8),
            (__attribute__((address_space(3))) unsigned int*)(Bsh + ch * 512),
            16, 0, 0);
    }

    const int b0 = bg * 16 + 2 * w;
    int xid[CPB][4];
#pragma unroll
    for (int c = 0; c < CPB; ++c)
#pragma unroll
        for (int mt = 0; mt < 4; ++mt)
            xid[c][mt] = X[(b0 + (mt >> 1)) * TDIM + (cg * CPB + c) * TC + (mt & 1) * 16 + col];

    const int hbase = hg * 64;
    float bz[4], bff[4];
#pragma unroll
    for (int nt = 0; nt < 4; ++nt) {
        bz[nt]  = bq[hbase + nt * 16 + col];
        bff[nt] = bq[HDIM + hbase + nt * 16 + col];
    }

    short8 abuf[3][4];
    auto fetchA = [&](int c, int ks, int slot) {
#pragma unroll
        for (int mt = 0; mt < 4; ++mt) {
            if constexpr (MODE == 1) {
                abuf[slot][mt] = *(const short8*)(ebf + (size_t)xid[c][mt] * EDIM + q * 8 + ks * 32);
            } else {
                const float* ap = emb + (size_t)xid[c][mt] * EDIM + q * 8 + ks * 32;
                floatx4 f0 = *(const floatx4*)ap;
                floatx4 f1 = *(const floatx4*)(ap + 4);
                uintx4 p = {pk2(f0.x, f0.y), pk2(f0.z, f0.w),
                            pk2(f1.x, f1.y), pk2(f1.z, f1.w)};
                abuf[slot][mt] = *(short8*)&p;
            }
        }
    };

    floatx4 acc[4][8];
#pragma unroll
    for (int mt = 0; mt < 4; ++mt)
#pragma unroll
        for (int nt = 0; nt < 8; ++nt) acc[mt][nt] = (floatx4){0.f, 0.f, 0.f, 0.f};

    fetchA(0, 0, 0);
    fetchA(0, 1, 1);
    __syncthreads();   // waits staging vmem too

#pragma unroll
    for (int c = 0; c < CPB; ++c) {
#pragma unroll
        for (int ks = 0; ks < 8; ++ks) {
            const int s = c * 8 + ks;
            if (s + 2 < CPB * 8)
                fetchA((s + 2) >> 3, (s + 2) & 7, (s + 2) % 3);
            short8 bf[8];
#pragma unroll
            for (int nt = 0; nt < 8; ++nt)
                bf[nt] = *(const short8*)(Bsh + (nt * 8 + ks) * 512 + lane * 8);
            const int sl = s % 3;
#pragma unroll
            for (int nt = 0; nt < 8; ++nt)
#pragma unroll
                for (int mt = 0; mt < 4; ++mt)
                    acc[mt][nt] = __builtin_amdgcn_mfma_f32_16x16x32_bf16(abuf[sl][mt], bf[nt], acc[mt][nt], 0, 0, 0);
        }

        // Epilogue for chunk cc: t = q*4 + j (+16*(mt&1)), h-col = nt*16+col.
        const int cc = cg * CPB + c;
        float Af0[4], Bf0[4], Af1[4], Bf1[4];
#pragma unroll
        for (int nt = 0; nt < 4; ++nt) {
            float Aseg[4], Bseg[4];
#pragma unroll
            for (int mt = 0; mt < 4; ++mt) {
                float Ac = 1.f, Bc = 0.f;
#pragma unroll
                for (int j = 0; j < 4; ++j) {
                    float z = tanh_fast(acc[mt][nt][j] + bz[nt]);
                    float f = sigm(acc[mt][nt + 4][j] + bff[nt]);
                    Ac = f * Ac;
                    Bc = fmaf(f, Bc, (1.f - f) * z);
                }
                Aseg[mt] = Ac; Bseg[mt] = Bc;
            }
#pragma unroll
            for (int st = 0; st < 2; ++st) {
                const int msk = 16 << st;
                const bool self_earlier = ((q >> st) & 1) == 0;
#pragma unroll
                for (int mt = 0; mt < 4; ++mt) {
                    float Ap = __shfl_xor(Aseg[mt], msk, 64);
                    float Bp = __shfl_xor(Bseg[mt], msk, 64);
                    Bseg[mt] = self_earlier ? fmaf(Ap, Bseg[mt], Bp)
                                            : fmaf(Aseg[mt], Bp, Bseg[mt]);
                    Aseg[mt] = Aseg[mt] * Ap;
                }
            }
            Af0[nt] = Aseg[0] * Aseg[1];
            Bf0[nt] = fmaf(Aseg[1], Bseg[0], Bseg[1]);
            Af1[nt] = Aseg[2] * Aseg[3];
            Bf1[nt] = fmaf(Aseg[3], Bseg[2], Bseg[3]);
        }

        float As0 = (q == 0) ? Af0[0] : (q == 1) ? Af0[1] : (q == 2) ? Af0[2] : Af0[3];
        float Bs0 = (q == 0) ? Bf0[0] : (q == 1) ? Bf0[1] : (q == 2) ? Bf0[2] : Bf0[3];
        float As1 = (q == 0) ? Af1[0] : (q == 1) ? Af1[1] : (q == 2) ? Af1[2] : Af1[3];
        float Bs1 = (q == 0) ? Bf1[0] : (q == 1) ? Bf1[1] : (q == 2) ? Bf1[2] : Bf1[3];

        const size_t r0 = ((size_t)cc * BDIM + b0) * HDIM + hbase + lane;
        wsA[r0] = As0;          wsB[r0] = Bs0;
        wsA[r0 + HDIM] = As1;   wsB[r0 + HDIM] = Bs1;

#pragma unroll
        for (int mt = 0; mt < 4; ++mt)
#pragma unroll
            for (int nt = 0; nt < 8; ++nt) acc[mt][nt] = (floatx4){0.f, 0.f, 0.f, 0.f};
    }
}

// Combine chunk (A,B) pairs + o-gate at t=T-1 + output dot.
__global__ __launch_bounds__(256) void qrnn_combine(
    const float* __restrict__ wsA, const float* __restrict__ wsB,
    const float* __restrict__ c0, const int* __restrict__ X,
    const float* __restrict__ emb, const float* __restrict__ Wq,
    const float* __restrict__ bq, const float* __restrict__ Wout,
    const float* __restrict__ bout, float* __restrict__ out)
{
    const int b = blockIdx.x;
    const int h = threadIdx.x;

    float c = c0[b * HDIM + h];
    for (int c8 = 0; c8 < NC; c8 += 8) {
        float a[8], bb[8];
#pragma unroll
        for (int i = 0; i < 8; ++i) {
            size_t base = ((size_t)(c8 + i) * BDIM + b) * HDIM + h;
            a[i]  = wsA[base];
            bb[i] = wsB[base];
        }
#pragma unroll
        for (int i = 0; i < 8; ++i) c = fmaf(a[i], c, bb[i]);
    }

    __shared__ float xs[EDIM];
    int idx = X[b * TDIM + (TDIM - 1)];
    xs[h] = emb[(size_t)idx * EDIM + h];
    __syncthreads();

    float acc = 0.f;
#pragma unroll 16
    for (int e = 0; e < EDIM; ++e)
        acc = fmaf(xs[e], Wq[e * (3 * HDIM) + 2 * HDIM + h], acc);

    float o  = 1.f / (1.f + expf(-(acc + bq[2 * HDIM + h])));
    float hn = o * c;

    __shared__ float red[HDIM];
    red[h] = hn * Wout[h];
    __syncthreads();
    for (int s = HDIM / 2; s > 0; s >>= 1) {
        if (h < s) red[h] += red[h + s];
        __syncthreads();
    }
    if (h == 0) out[b] = red[0] + bout[0];
}

extern "C" void kernel_launch(void* const* d_in, const int* in_sizes, int n_in,
                              void* d_out, int out_size, void* d_ws, size_t ws_size,
                              hipStream_t stream) {
    const int*   X    = (const int*)d_in[0];
    const float* emb  = (const float*)d_in[1];
    const float* Wq   = (const float*)d_in[2];
    const float* bq   = (const float*)d_in[3];
    const float* c0   = (const float*)d_in[4];
    const float* Wout = (const float*)d_in[5];
    const float* bout = (const float*)d_in[6];
    float* out = (float*)d_out;

    float* wsA = (float*)d_ws;                        // [NC][B][H]
    float* wsB = wsA + (size_t)NC * BDIM * HDIM;      // [NC][B][H]
    unsigned short* Wp  = (unsigned short*)(wsB + (size_t)NC * BDIM * HDIM);  // 256 KB
    unsigned short* ebf = Wp + (size_t)256 * 512;     // 16.4 MB bf16 emb table

    const size_t wsAB = (size_t)2 * NC * BDIM * HDIM * 4;
    const size_t wpsz = (size_t)256 * 512 * 2;
    const size_t need1 = wsAB + wpsz + (size_t)32000 * EDIM * 2;   // ~25.0 MB
    const int mode = (ws_size >= need1) ? 1 : 0;

    const int gather_blocks = (mode == 1) ? (32000 * EDIM / 8) / 256 : 0;  // 4000
    qrnn_pack<<<256 + gather_blocks, 256, 0, stream>>>(Wq, emb, Wp, ebf, mode);

    dim3 g(NC / CPB, BDIM / 16, HDIM / 64);   // 32 x 4 x 4 = 512 blocks of 512 thr (2/CU)
    if (mode == 1) qrnn_mfma<1><<<g, 512, 0, stream>>>(X, emb, ebf, Wp, bq, wsA, wsB);
    else           qrnn_mfma<0><<<g, 512, 0, stream>>>(X, emb, ebf, Wp, bq, wsA, wsB);

    qrnn_combine<<<BDIM, 256, 0, stream>>>(wsA, wsB, c0, X, emb, Wq, bq, Wout, bout, out);
}

// Round 5
// 226.673 us; speedup vs baseline: 2.1192x; 2.1192x over previous
//
#include <hip/hip_runtime.h>
#include <hip/hip_bf16.h>
#include <math.h>

#define VOCAB 32000
#define EDIM 256
#define HDIM 256
#define BDIM 64
#define TDIM 2048
#define NC   64
#define TC   32
#define CPB  4      // chunks per persistent block
#define NBLK 512    // total blocks; == 256 CU x 2 blocks/CU (co-residency exact fit)

typedef __attribute__((ext_vector_type(8)))  short  short8;
typedef __attribute__((ext_vector_type(4)))  float  floatx4;
typedef __attribute__((ext_vector_type(4)))  unsigned int uintx4;

__device__ __forceinline__ unsigned short f2bf(float f) {
    unsigned int u = __float_as_uint(f);
    u += 0x7FFFu + ((u >> 16) & 1u);      // RNE
    return (unsigned short)(u >> 16);
}
__device__ __forceinline__ unsigned int pk2(float a, float b) {
    return (unsigned int)f2bf(a) | ((unsigned int)f2bf(b) << 16);
}
__device__ __forceinline__ float sigm(float x) {
    return __builtin_amdgcn_rcpf(1.f + __expf(-x));
}
__device__ __forceinline__ float tanh_fast(float x) {
    return fmaf(-2.f, __builtin_amdgcn_rcpf(1.f + __expf(2.f * x)), 1.f);
}

// Single fused kernel.  512 blocks x 256 thr, __launch_bounds__(256,2):
// NOTE: on this toolchain the 2nd arg is min BLOCKS/CU (R3 evidence: (512,4)
// forced 64 VGPR = 2048/32).  (256,2) -> 8 waves/CU -> reg cap 256 = what the
// R0 kernel already used.  LDS 64KB -> exactly 2 blocks/CU -> all 512 blocks
// co-resident, so device-scope atomic grid barriers are safe.
//
// Phase 0: build Bsh (weights, fragment layout) straight from Wq (no Wp
//          table, no pack dispatch) + convert emb -> bf16 table (MODE 1).
// Barrier 1 (agent scope, all 512).
// Phase 1: R0 mfma chunk loop, verbatim.
// Barrier 2: signal-and-exit for blocks >= 64.
// Phase 2: combine (c-scan join + o-gate + output dot) in blocks 0..63.
template<int MODE>
__global__ __launch_bounds__(256, 2) void qrnn_fused(
    const int* __restrict__ X, const float* __restrict__ emb,
    const float* __restrict__ Wq, const float* __restrict__ bq,
    const float* __restrict__ c0, const float* __restrict__ Wout,
    const float* __restrict__ bout,
    unsigned short* __restrict__ ebf, float* __restrict__ wsA,
    float* __restrict__ wsB, unsigned int* __restrict__ cnt,
    float* __restrict__ out)
{
    __shared__ __align__(16) short Bsh[32768];   // 64 KB: [nt*8+ks][64 lanes][8]

    const int tid = threadIdx.x;
    const int cg = blockIdx.x, bg = blockIdx.y, hg = blockIdx.z;
    const int fid = cg + 16 * bg + 128 * hg;     // grid (16,8,4) -> 512
    const int lane = tid & 63, w = tid >> 6;
    const int col = lane & 15, q = lane >> 4;

    // ---- Phase 0a: Bsh for this hg directly from Wq (L2-hot, 768KB table).
    {
        const int l2 = tid >> 2, pj = tid & 3;   // l2 = dest lane, pj = k-pair
        const int dcol = l2 & 15, dq = l2 >> 4;
#pragma unroll 4
        for (int ch = 0; ch < 64; ++ch) {
            const int nt = ch >> 3, ks = ch & 7;
            const int h = hg * 64 + (nt & 3) * 16 + dcol;
            const int c = (nt < 4) ? h : (HDIM + h);
            const int k = ks * 32 + dq * 8 + pj * 2;
            unsigned int v = pk2(Wq[k * (3 * HDIM) + c], Wq[(k + 1) * (3 * HDIM) + c]);
            *(unsigned int*)(Bsh + ch * 512 + l2 * 8 + pj * 2) = v;
        }
    }

    // ---- Phase 0b: emb -> bf16 slice (grid-stride over 1,024,000 groups of 8).
    if constexpr (MODE == 1) {
        for (int g = fid * 256 + tid; g < (VOCAB * EDIM / 8); g += NBLK * 256) {
            const float* src = emb + (size_t)g * 8;
            floatx4 a = *(const floatx4*)src;
            floatx4 b = *(const floatx4*)(src + 4);
            uintx4 o = {pk2(a.x, a.y), pk2(a.z, a.w), pk2(b.x, b.y), pk2(b.z, b.w)};
            *(uintx4*)(ebf + (size_t)g * 8) = o;
        }
    }

    // Read-only per-wave setup (same as R0).
    const int b0 = bg * 8 + 2 * w;
    int xid[CPB][4];
#pragma unroll
    for (int c = 0; c < CPB; ++c)
#pragma unroll
        for (int mt = 0; mt < 4; ++mt)
            xid[c][mt] = X[(b0 + (mt >> 1)) * TDIM + (cg * CPB + c) * TC + (mt & 1) * 16 + col];

    const int hbase = hg * 64;
    float bz[4], bff[4];
#pragma unroll
    for (int nt = 0; nt < 4; ++nt) {
        bz[nt]  = bq[hbase + nt * 16 + col];
        bff[nt] = bq[HDIM + hbase + nt * 16 + col];
    }

    // ---- Grid barrier 1: ebf ready (also covers Bsh ds_writes via s_barrier).
    __syncthreads();                              // drains vmem + lds writes
    if constexpr (MODE == 1) {
        if (tid == 0) {
            __hip_atomic_fetch_add(&cnt[0], 1u, __ATOMIC_ACQ_REL, __HIP_MEMORY_SCOPE_AGENT);
            unsigned int v;
            do {
                __builtin_amdgcn_s_sleep(32);
                v = __hip_atomic_load(&cnt[0], __ATOMIC_RELAXED, __HIP_MEMORY_SCOPE_AGENT);
            } while (v < NBLK);
        }
        __syncthreads();
        __builtin_amdgcn_fence(__ATOMIC_ACQUIRE, "agent");
    }

    // ---- Phase 1: R0 mfma chunk loop (verbatim). ----
    short8 abuf[3][4];
    auto fetchA = [&](int c, int ks, int slot) {
#pragma unroll
        for (int mt = 0; mt < 4; ++mt) {
            if constexpr (MODE == 1) {
                abuf[slot][mt] = *(const short8*)(ebf + (size_t)xid[c][mt] * EDIM + q * 8 + ks * 32);
            } else {
                const float* ap = emb + (size_t)xid[c][mt] * EDIM + q * 8 + ks * 32;
                floatx4 f0 = *(const floatx4*)ap;
                floatx4 f1 = *(const floatx4*)(ap + 4);
                uintx4 p = {pk2(f0.x, f0.y), pk2(f0.z, f0.w),
                            pk2(f1.x, f1.y), pk2(f1.z, f1.w)};
                abuf[slot][mt] = *(short8*)&p;
            }
        }
    };

    floatx4 acc[4][8];
#pragma unroll
    for (int mt = 0; mt < 4; ++mt)
#pragma unroll
        for (int nt = 0; nt < 8; ++nt) acc[mt][nt] = (floatx4){0.f, 0.f, 0.f, 0.f};

    fetchA(0, 0, 0);
    fetchA(0, 1, 1);

#pragma unroll
    for (int c = 0; c < CPB; ++c) {
#pragma unroll
        for (int ks = 0; ks < 8; ++ks) {
            const int s = c * 8 + ks;
            if (s + 2 < CPB * 8)
                fetchA((s + 2) >> 3, (s + 2) & 7, (s + 2) % 3);
            short8 bf[8];
#pragma unroll
            for (int nt = 0; nt < 8; ++nt)
                bf[nt] = *(const short8*)(Bsh + (nt * 8 + ks) * 512 + lane * 8);
            const int sl = s % 3;
#pragma unroll
            for (int nt = 0; nt < 8; ++nt)
#pragma unroll
                for (int mt = 0; mt < 4; ++mt)
                    acc[mt][nt] = __builtin_amdgcn_mfma_f32_16x16x32_bf16(abuf[sl][mt], bf[nt], acc[mt][nt], 0, 0, 0);
        }

        // Epilogue for chunk cc: t = q*4 + j (+16*(mt&1)), h-col = nt*16+col.
        const int cc = cg * CPB + c;
        float Af0[4], Bf0[4], Af1[4], Bf1[4];
#pragma unroll
        for (int nt = 0; nt < 4; ++nt) {
            float Aseg[4], Bseg[4];
#pragma unroll
            for (int mt = 0; mt < 4; ++mt) {
                float Ac = 1.f, Bc = 0.f;
#pragma unroll
                for (int j = 0; j < 4; ++j) {
                    float z = tanh_fast(acc[mt][nt][j] + bz[nt]);
                    float f = sigm(acc[mt][nt + 4][j] + bff[nt]);
                    Ac = f * Ac;
                    Bc = fmaf(f, Bc, (1.f - f) * z);
                }
                Aseg[mt] = Ac; Bseg[mt] = Bc;
            }
#pragma unroll
            for (int st = 0; st < 2; ++st) {
                const int msk = 16 << st;
                const bool self_earlier = ((q >> st) & 1) == 0;
#pragma unroll
                for (int mt = 0; mt < 4; ++mt) {
                    float Ap = __shfl_xor(Aseg[mt], msk, 64);
                    float Bp = __shfl_xor(Bseg[mt], msk, 64);
                    Bseg[mt] = self_earlier ? fmaf(Ap, Bseg[mt], Bp)
                                            : fmaf(Aseg[mt], Bp, Bseg[mt]);
                    Aseg[mt] = Aseg[mt] * Ap;
                }
            }
            Af0[nt] = Aseg[0] * Aseg[1];
            Bf0[nt] = fmaf(Aseg[1], Bseg[0], Bseg[1]);
            Af1[nt] = Aseg[2] * Aseg[3];
            Bf1[nt] = fmaf(Aseg[3], Bseg[2], Bseg[3]);
        }

        float As0 = (q == 0) ? Af0[0] : (q == 1) ? Af0[1] : (q == 2) ? Af0[2] : Af0[3];
        float Bs0 = (q == 0) ? Bf0[0] : (q == 1) ? Bf0[1] : (q == 2) ? Bf0[2] : Bf0[3];
        float As1 = (q == 0) ? Af1[0] : (q == 1) ? Af1[1] : (q == 2) ? Af1[2] : Af1[3];
        float Bs1 = (q == 0) ? Bf1[0] : (q == 1) ? Bf1[1] : (q == 2) ? Bf1[2] : Bf1[3];

        const size_t r0 = ((size_t)cc * BDIM + b0) * HDIM + hbase + lane;
        wsA[r0] = As0;          wsB[r0] = Bs0;
        wsA[r0 + HDIM] = As1;   wsB[r0 + HDIM] = Bs1;

#pragma unroll
        for (int mt = 0; mt < 4; ++mt)
#pragma unroll
            for (int nt = 0; nt < 8; ++nt) acc[mt][nt] = (floatx4){0.f, 0.f, 0.f, 0.f};
    }

    // ---- Grid barrier 2: wsA/wsB ready.  Non-combine blocks signal & exit.
    __syncthreads();                              // drains the wsA/wsB stores
    if (tid == 0)
        __hip_atomic_fetch_add(&cnt[1], 1u, __ATOMIC_ACQ_REL, __HIP_MEMORY_SCOPE_AGENT);
    if (fid >= BDIM) return;
    if (tid == 0) {
        unsigned int v;
        do {
            __builtin_amdgcn_s_sleep(32);
            v = __hip_atomic_load(&cnt[1], __ATOMIC_RELAXED, __HIP_MEMORY_SCOPE_AGENT);
        } while (v < NBLK);
    }
    __syncthreads();
    __builtin_amdgcn_fence(__ATOMIC_ACQUIRE, "agent");

    // ---- Phase 2: combine for b = fid (blocks 0..63). ----
    {
        const int b = fid;
        const int h = tid;

        float cacc = c0[b * HDIM + h];
        for (int c8 = 0; c8 < NC; c8 += 8) {
            float a[8], bb[8];
#pragma unroll
            for (int i = 0; i < 8; ++i) {
                size_t base = ((size_t)(c8 + i) * BDIM + b) * HDIM + h;
                a[i]  = wsA[base];
                bb[i] = wsB[base];
            }
#pragma unroll
            for (int i = 0; i < 8; ++i) cacc = fmaf(a[i], cacc, bb[i]);
        }

        float* xs = (float*)Bsh;                  // reuse LDS (phase 1 done)
        float* red = (float*)Bsh + EDIM;
        int idx = X[b * TDIM + (TDIM - 1)];
        xs[h] = emb[(size_t)idx * EDIM + h];
        __syncthreads();

        float dacc = 0.f;
#pragma unroll 16
        for (int e = 0; e < EDIM; ++e)
            dacc = fmaf(xs[e], Wq[e * (3 * HDIM) + 2 * HDIM + h], dacc);

        float o  = 1.f / (1.f + expf(-(dacc + bq[2 * HDIM + h])));
        float hn = o * cacc;

        red[h] = hn * Wout[h];
        __syncthreads();
        for (int s = HDIM / 2; s > 0; s >>= 1) {
            if (h < s) red[h] += red[h + s];
            __syncthreads();
        }
        if (h == 0) out[b] = red[0] + bout[0];
    }
}

extern "C" void kernel_launch(void* const* d_in, const int* in_sizes, int n_in,
                              void* d_out, int out_size, void* d_ws, size_t ws_size,
                              hipStream_t stream) {
    const int*   X    = (const int*)d_in[0];
    const float* emb  = (const float*)d_in[1];
    const float* Wq   = (const float*)d_in[2];
    const float* bq   = (const float*)d_in[3];
    const float* c0   = (const float*)d_in[4];
    const float* Wout = (const float*)d_in[5];
    const float* bout = (const float*)d_in[6];
    float* out = (float*)d_out;

    // Workspace layout: [0,256) barrier counters | wsA | wsB | ebf.
    unsigned int* cnt = (unsigned int*)d_ws;
    float* wsA = (float*)((char*)d_ws + 256);         // [NC][B][H]
    float* wsB = wsA + (size_t)NC * BDIM * HDIM;      // [NC][B][H]
    unsigned short* ebf = (unsigned short*)(wsB + (size_t)NC * BDIM * HDIM);

    const size_t wsAB  = (size_t)2 * NC * BDIM * HDIM * 4;
    const size_t need1 = 256 + wsAB + (size_t)VOCAB * EDIM * 2;   // ~24.8 MB
    const int mode = (ws_size >= need1) ? 1 : 0;

    (void)hipMemsetAsync(cnt, 0, 16, stream);   // re-arm barrier counters each replay

    dim3 g(NC / CPB, BDIM / 8, HDIM / 64);   // 16 x 8 x 4 = 512 blocks (2/CU exact)
    if (mode == 1)
        qrnn_fused<1><<<g, 256, 0, stream>>>(X, emb, Wq, bq, c0, Wout, bout,
                                             ebf, wsA, wsB, cnt, out);
    else
        qrnn_fused<0><<<g, 256, 0, stream>>>(X, emb, Wq, bq, c0, Wout, bout,
                                             ebf, wsA, wsB, cnt, out);
}

// Round 6
// 150.268 us; speedup vs baseline: 3.1968x; 1.5085x over previous
//
#include <hip/hip_runtime.h>
#include <hip/hip_bf16.h>
#include <math.h>

#define EDIM 256
#define HDIM 256
#define BDIM 64
#define TDIM 2048
#define NC   64
#define TC   32
#define CPB  4      // chunks per persistent block

typedef __attribute__((ext_vector_type(8)))  short  short8;
typedef __attribute__((ext_vector_type(4)))  float  floatx4;
typedef __attribute__((ext_vector_type(4)))  unsigned int uintx4;

__device__ __forceinline__ unsigned short f2bf(float f) {
    unsigned int u = __float_as_uint(f);
    u += 0x7FFFu + ((u >> 16) & 1u);      // RNE
    return (unsigned short)(u >> 16);
}
__device__ __forceinline__ unsigned int pk2(float a, float b) {
    return (unsigned int)f2bf(a) | ((unsigned int)f2bf(b) << 16);
}
__device__ __forceinline__ float sigm(float x) {
    return __builtin_amdgcn_rcpf(1.f + __expf(-x));
}
__device__ __forceinline__ float tanh_fast(float x) {
    return fmaf(-2.f, __builtin_amdgcn_rcpf(1.f + __expf(2.f * x)), 1.f);
}

// Pack kernel:
//  bx < 256 : Wp fragment-pack (R0 layout, unchanged).
//  bx >= 256 (mode==1): emb -> bf16 table.
__global__ __launch_bounds__(256) void qrnn_pack(
    const float* __restrict__ Wq, const float* __restrict__ emb,
    unsigned short* __restrict__ Wp, unsigned short* __restrict__ ebf,
    int mode)
{
    const int bx = blockIdx.x;
    if (bx < 256) {
        const int nt = (bx >> 3) & 7;
        const int hg = bx >> 6;
        const int ks = bx & 7;
        const int t = threadIdx.x;
        const int lane = t >> 2, pj = t & 3;
        const int col = lane & 15, q = lane >> 4;
        const int h = hg * 64 + (nt & 3) * 16 + col;
        const int c = (nt < 4) ? h : (HDIM + h);
        const int k = ks * 32 + q * 8 + pj * 2;
        unsigned int v = pk2(Wq[k * (3 * HDIM) + c], Wq[(k + 1) * (3 * HDIM) + c]);
        *(unsigned int*)(Wp + (size_t)bx * 512 + lane * 8 + pj * 2) = v;
    } else if (mode == 1) {
        size_t i = ((size_t)(bx - 256) * 256 + threadIdx.x) * 8;
        floatx4 a = *(const floatx4*)(emb + i);
        floatx4 b = *(const floatx4*)(emb + i + 4);
        uintx4 o = {pk2(a.x, a.y), pk2(a.z, a.w), pk2(b.x, b.y), pk2(b.z, b.w)};
        *(uintx4*)(ebf + i) = o;
    }
}

// Main: R0 structure with the per-wave tile HALVED and waves/block DOUBLED.
// 512 blocks x 512 thr (8 waves).  Each wave: 1 batch x 64 h x 4 chunks
// (acc[2][8], abuf[3][2]) vs R0's 2 batches (acc[4][8]).  Same total work,
// same 64KB Bsh, same A-gather traffic -- but 2 blocks/CU x 8 waves =
// 16 waves/CU = 4 waves/SIMD (2x R0's TLP; LDS was the binding limit and
// registers have huge headroom: ~180/wave vs 512 cap at 4/SIMD).
// __launch_bounds__ 2nd arg = min BLOCKS/CU on this toolchain (R3 evidence).
template<int MODE>
__global__ __launch_bounds__(512, 2) void qrnn_mfma(
    const int* __restrict__ X, const float* __restrict__ emb,
    const unsigned short* __restrict__ ebf, const unsigned short* __restrict__ Wp,
    const float* __restrict__ bq, float* __restrict__ wsA, float* __restrict__ wsB)
{
    __shared__ __align__(16) short Bsh[32768];   // 64 KB: [nt*8+ks][64 lanes][8]

    const int tid = threadIdx.x;
    const int cg = blockIdx.x, bg = blockIdx.y, hg = blockIdx.z;
    const int lane = tid & 63, w = tid >> 6;     // w in [0,8)
    const int col = lane & 15, q = lane >> 4;

    // Stage B slice (64 KB, all ks) once: 64 rows / 8 waves = 8 each.
    const unsigned short* wpb = Wp + (size_t)hg * 32768;
#pragma unroll
    for (int i = 0; i < 8; ++i) {
        const int ch = w * 8 + i;           // wave-uniform
        __builtin_amdgcn_global_load_lds(
            (const __attribute__((address_space(1))) unsigned int*)(wpb + ch * 512 + lane * 8),
            (__attribute__((address_space(3))) unsigned int*)(Bsh + ch * 512),
            16, 0, 0);
    }

    const int b0 = bg * 8 + w;              // one batch per wave
    int xid[CPB][2];
#pragma unroll
    for (int c = 0; c < CPB; ++c)
#pragma unroll
        for (int mt = 0; mt < 2; ++mt)
            xid[c][mt] = X[b0 * TDIM + (cg * CPB + c) * TC + mt * 16 + col];

    const int hbase = hg * 64;
    float bz[4], bff[4];
#pragma unroll
    for (int nt = 0; nt < 4; ++nt) {
        bz[nt]  = bq[hbase + nt * 16 + col];
        bff[nt] = bq[HDIM + hbase + nt * 16 + col];
    }

    short8 abuf[3][2];
    auto fetchA = [&](int c, int ks, int slot) {
#pragma unroll
        for (int mt = 0; mt < 2; ++mt) {
            if constexpr (MODE == 1) {
                abuf[slot][mt] = *(const short8*)(ebf + (size_t)xid[c][mt] * EDIM + q * 8 + ks * 32);
            } else {
                const float* ap = emb + (size_t)xid[c][mt] * EDIM + q * 8 + ks * 32;
                floatx4 f0 = *(const floatx4*)ap;
                floatx4 f1 = *(const floatx4*)(ap + 4);
                uintx4 p = {pk2(f0.x, f0.y), pk2(f0.z, f0.w),
                            pk2(f1.x, f1.y), pk2(f1.z, f1.w)};
                abuf[slot][mt] = *(short8*)&p;
            }
        }
    };

    floatx4 acc[2][8];
#pragma unroll
    for (int mt = 0; mt < 2; ++mt)
#pragma unroll
        for (int nt = 0; nt < 8; ++nt) acc[mt][nt] = (floatx4){0.f, 0.f, 0.f, 0.f};

    fetchA(0, 0, 0);
    fetchA(0, 1, 1);
    __syncthreads();   // waits staging vmem too

#pragma unroll
    for (int c = 0; c < CPB; ++c) {
#pragma unroll
        for (int ks = 0; ks < 8; ++ks) {
            const int s = c * 8 + ks;
            if (s + 2 < CPB * 8)
                fetchA((s + 2) >> 3, (s + 2) & 7, (s + 2) % 3);
            short8 bf[8];
#pragma unroll
            for (int nt = 0; nt < 8; ++nt)
                bf[nt] = *(const short8*)(Bsh + (nt * 8 + ks) * 512 + lane * 8);
            const int sl = s % 3;
#pragma unroll
            for (int nt = 0; nt < 8; ++nt)
#pragma unroll
                for (int mt = 0; mt < 2; ++mt)
                    acc[mt][nt] = __builtin_amdgcn_mfma_f32_16x16x32_bf16(abuf[sl][mt], bf[nt], acc[mt][nt], 0, 0, 0);
        }

        // Epilogue for chunk cc: t = q*4 + j (+16*mt), h-col = nt*16+col.
        const int cc = cg * CPB + c;
        float Af[4], Bf[4];
#pragma unroll
        for (int nt = 0; nt < 4; ++nt) {
            float Aseg[2], Bseg[2];
#pragma unroll
            for (int mt = 0; mt < 2; ++mt) {
                float Ac = 1.f, Bc = 0.f;
#pragma unroll
                for (int j = 0; j < 4; ++j) {
                    float z = tanh_fast(acc[mt][nt][j] + bz[nt]);
                    float f = sigm(acc[mt][nt + 4][j] + bff[nt]);
                    Ac = f * Ac;
                    Bc = fmaf(f, Bc, (1.f - f) * z);
                }
                Aseg[mt] = Ac; Bseg[mt] = Bc;
            }
            // Scan across q-groups (t = q*4+j within each 16-t half).
#pragma unroll
            for (int st = 0; st < 2; ++st) {
                const int msk = 16 << st;
                const bool self_earlier = ((q >> st) & 1) == 0;
#pragma unroll
                for (int mt = 0; mt < 2; ++mt) {
                    float Ap = __shfl_xor(Aseg[mt], msk, 64);
                    float Bp = __shfl_xor(Bseg[mt], msk, 64);
                    Bseg[mt] = self_earlier ? fmaf(Ap, Bseg[mt], Bp)
                                            : fmaf(Aseg[mt], Bp, Bseg[mt]);
                    Aseg[mt] = Aseg[mt] * Ap;
                }
            }
            Af[nt] = Aseg[0] * Aseg[1];                 // full 32-t chunk, batch b0
            Bf[nt] = fmaf(Aseg[1], Bseg[0], Bseg[1]);
        }

        float As = (q == 0) ? Af[0] : (q == 1) ? Af[1] : (q == 2) ? Af[2] : Af[3];
        float Bs = (q == 0) ? Bf[0] : (q == 1) ? Bf[1] : (q == 2) ? Bf[2] : Bf[3];

        const size_t r0 = ((size_t)cc * BDIM + b0) * HDIM + hbase + lane;
        wsA[r0] = As;
        wsB[r0] = Bs;

#pragma unroll
        for (int mt = 0; mt < 2; ++mt)
#pragma unroll
            for (int nt = 0; nt < 8; ++nt) acc[mt][nt] = (floatx4){0.f, 0.f, 0.f, 0.f};
    }
}

// Combine chunk (A,B) pairs + o-gate at t=T-1 + output dot.
__global__ __launch_bounds__(256) void qrnn_combine(
    const float* __restrict__ wsA, const float* __restrict__ wsB,
    const float* __restrict__ c0, const int* __restrict__ X,
    const float* __restrict__ emb, const float* __restrict__ Wq,
    const float* __restrict__ bq, const float* __restrict__ Wout,
    const float* __restrict__ bout, float* __restrict__ out)
{
    const int b = blockIdx.x;
    const int h = threadIdx.x;

    float c = c0[b * HDIM + h];
    for (int c8 = 0; c8 < NC; c8 += 8) {
        float a[8], bb[8];
#pragma unroll
        for (int i = 0; i < 8; ++i) {
            size_t base = ((size_t)(c8 + i) * BDIM + b) * HDIM + h;
            a[i]  = wsA[base];
            bb[i] = wsB[base];
        }
#pragma unroll
        for (int i = 0; i < 8; ++i) c = fmaf(a[i], c, bb[i]);
    }

    __shared__ float xs[EDIM];
    int idx = X[b * TDIM + (TDIM - 1)];
    xs[h] = emb[(size_t)idx * EDIM + h];
    __syncthreads();

    float acc = 0.f;
#pragma unroll 16
    for (int e = 0; e < EDIM; ++e)
        acc = fmaf(xs[e], Wq[e * (3 * HDIM) + 2 * HDIM + h], acc);

    float o  = 1.f / (1.f + expf(-(acc + bq[2 * HDIM + h])));
    float hn = o * c;

    __shared__ float red[HDIM];
    red[h] = hn * Wout[h];
    __syncthreads();
    for (int s = HDIM / 2; s > 0; s >>= 1) {
        if (h < s) red[h] += red[h + s];
        __syncthreads();
    }
    if (h == 0) out[b] = red[0] + bout[0];
}

extern "C" void kernel_launch(void* const* d_in, const int* in_sizes, int n_in,
                              void* d_out, int out_size, void* d_ws, size_t ws_size,
                              hipStream_t stream) {
    const int*   X    = (const int*)d_in[0];
    const float* emb  = (const float*)d_in[1];
    const float* Wq   = (const float*)d_in[2];
    const float* bq   = (const float*)d_in[3];
    const float* c0   = (const float*)d_in[4];
    const float* Wout = (const float*)d_in[5];
    const float* bout = (const float*)d_in[6];
    float* out = (float*)d_out;

    float* wsA = (float*)d_ws;                        // [NC][B][H]
    float* wsB = wsA + (size_t)NC * BDIM * HDIM;      // [NC][B][H]
    unsigned short* Wp  = (unsigned short*)(wsB + (size_t)NC * BDIM * HDIM);  // 256 KB
    unsigned short* ebf = Wp + (size_t)256 * 512;     // 16.4 MB bf16 emb table

    const size_t wsAB = (size_t)2 * NC * BDIM * HDIM * 4;
    const size_t wpsz = (size_t)256 * 512 * 2;
    const size_t need1 = wsAB + wpsz + (size_t)32000 * EDIM * 2;   // ~25.0 MB
    const int mode = (ws_size >= need1) ? 1 : 0;

    const int gather_blocks = (mode == 1) ? (32000 * EDIM / 8) / 256 : 0;  // 4000
    qrnn_pack<<<256 + gather_blocks, 256, 0, stream>>>(Wq, emb, Wp, ebf, mode);

    dim3 g(NC / CPB, BDIM / 8, HDIM / 64);   // 16 x 8 x 4 = 512 blocks of 512 thr (2/CU)
    if (mode == 1) qrnn_mfma<1><<<g, 512, 0, stream>>>(X, emb, ebf, Wp, bq, wsA, wsB);
    else           qrnn_mfma<0><<<g, 512, 0, stream>>>(X, emb, ebf, Wp, bq, wsA, wsB);

    qrnn_combine<<<BDIM, 256, 0, stream>>>(wsA, wsB, c0, X, emb, Wq, bq, Wout, bout, out);
}